// Round 11
// baseline (244.878 us; speedup 1.0000x reference)
//
#include <hip/hip_runtime.h>
#include <hip/hip_fp16.h>

// GraphFlow GCN: 3x (linear -> normalized aggregation + self-loop -> bias [+tanh])
// N=100000, E=1600000.
// R11: 8-byte CSR records {row, fp32 w} (weight decode = bitcast, q15->f32 done
// once in bucket2) + native _Float16 casts in gathers so clang fuses cvt+fma
// into v_fma_mix_f32 (8 mix vs 8 cvt + 8 fma per lane-edge). Gathers were
// VALU-bound at 72% VALUBusy. Rest unchanged from R10.

static inline int cdiv64(long long a, int b) { return (int)((a + b - 1) / b); }

#define BSH 8            // 256 cols per bucket
#define BCAP 8192        // max records per bucket (avg 4092)
#define CHUNK 4096       // edges per pass-1 block

typedef _Float16 half8v __attribute__((ext_vector_type(8)));
union F4H8 { float4 f4; half8v h; };

__device__ __forceinline__ float tanh_fast(float x) {
  float t = __expf(2.0f * x);
  float r = __builtin_amdgcn_rcpf(t + 1.0f);
  return fmaf(-2.0f, r, 1.0f);
}

__global__ void zero_kernel(int4* __restrict__ p, int n4) {
  int i = blockIdx.x * blockDim.x + threadIdx.x;
  if (i < n4) p[i] = make_int4(0, 0, 0, 0);
}

// Pass 1: coarse bucket partition (LDS histogram, one global cursor atomic per
// (block,bucket), burst writes into bucket regions).
__global__ __launch_bounds__(256) void bucket1_kernel(
    const int* __restrict__ row, const int* __restrict__ col,
    const float* __restrict__ ew, int* __restrict__ gcur,
    uint2* __restrict__ btmp, int nE, int nb) {
  __shared__ int hcnt[512];
  __shared__ int gbase[512];
  const int tid = threadIdx.x;
  const int e0 = blockIdx.x * CHUNK;
  const int cnt_e = min(CHUNK, nE - e0);
  for (int i = tid; i < nb; i += 256) hcnt[i] = 0;
  __syncthreads();

  uint2 recs[CHUNK / 256];
  int   bs[CHUNK / 256];
  int   lis[CHUNK / 256];
#pragma unroll
  for (int p = 0; p < CHUNK / 256; ++p) {
    int k = tid + p * 256;
    bool valid = k < cnt_e;
    int e = e0 + (valid ? k : 0);
    int c = col[e];
    unsigned q = __float2uint_rn(ew[e] * 32768.0f);
    if (q > 32767u) q = 32767u;
    uint2 r;
    r.x = (q << 17) | (unsigned)row[e];
    r.y = (unsigned)c;
    int b = c >> BSH;
    recs[p] = r;
    bs[p] = valid ? b : -1;
    lis[p] = valid ? atomicAdd(&hcnt[b], 1) : 0;
  }
  __syncthreads();
  for (int i = tid; i < nb; i += 256)
    gbase[i] = hcnt[i] ? atomicAdd(&gcur[i], hcnt[i]) : 0;
  __syncthreads();
#pragma unroll
  for (int p = 0; p < CHUNK / 256; ++p) {
    int b = bs[p];
    if (b >= 0) {
      int idx = gbase[b] + lis[p];
      if (idx < BCAP) btmp[((size_t)b << 13) + idx] = recs[p];
    }
  }
}

// Pass 2: one WG per bucket -> exact CSR (8B records {row, f32 w}) +
// {start,cnt} node table + dis. All random accesses in LDS.
__global__ __launch_bounds__(256) void bucket2_kernel(
    const int* __restrict__ gcur, const uint2* __restrict__ btmp,
    uint2* __restrict__ ce, int2* __restrict__ node2,
    float* __restrict__ dis, int n) {
  __shared__ uint2 recs[BCAP];          // 64 KB
  __shared__ uint2 stageA[BCAP / 2];    // 32 KB
  __shared__ uint2 stageB[BCAP / 2];    // 32 KB
  __shared__ unsigned cnt[256], sumq[256], start[256], cur[256], scanbuf[256];
  const int tid = threadIdx.x;
  const int b = blockIdx.x;
  const int cb = min(gcur[b], BCAP);
  const int colbase = b << BSH;
  const int ncols = min(256, n - colbase);

  cnt[tid] = 0; sumq[tid] = 0; cur[tid] = 0;
  const uint2* src = btmp + ((size_t)b << 13);
  for (int k = tid; k < cb; k += 256) recs[k] = src[k];
  __syncthreads();
  for (int k = tid; k < cb; k += 256) {
    unsigned cl = recs[k].y & 255u;
    atomicAdd(&cnt[cl], 1u);
    atomicAdd(&sumq[cl], recs[k].x >> 17);
  }
  __syncthreads();
  unsigned v = cnt[tid];
  unsigned incl = v;
  scanbuf[tid] = incl;
  __syncthreads();
  for (int off = 1; off < 256; off <<= 1) {
    unsigned add = (tid >= off) ? scanbuf[tid - off] : 0u;
    __syncthreads();
    incl += add;
    scanbuf[tid] = incl;
    __syncthreads();
  }
  start[tid] = incl - v;
  __syncthreads();
  for (int k = tid; k < cb; k += 256) {
    unsigned rw = recs[k].x;
    unsigned cl = recs[k].y & 255u;
    unsigned p = start[cl] + atomicAdd(&cur[cl], 1u);
    uint2 o;
    o.x = rw & 0x1FFFFu;
    o.y = __float_as_uint((float)(rw >> 17) * 3.0517578125e-05f);
    if (p < (unsigned)(BCAP / 2)) stageA[p] = o;
    else stageB[p - BCAP / 2] = o;
  }
  __syncthreads();
  const unsigned base = (unsigned)b << 13;
  for (int k = tid; k < cb; k += 256)
    ce[base + k] = (k < BCAP / 2) ? stageA[k] : stageB[k - BCAP / 2];
  if (tid < ncols) {
    node2[colbase + tid] = make_int2((int)(base + start[tid]), (int)cnt[tid]);
    float deg = (float)sumq[tid] * 3.0517578125e-05f + 1.0f;
    dis[colbase + tid] = rsqrtf(deg);
  }
}

// Tiled layer-1 GEMM, fused time-channel concat + dis row-scale.
__global__ __launch_bounds__(256) void gemm1_tiled(const float* __restrict__ data,
                                                   const float* __restrict__ tptr,
                                                   const float* __restrict__ W,
                                                   const float* __restrict__ dis,
                                                   __half2* __restrict__ y, int n) {
  __shared__ float Ws[64 * 64];
  __shared__ float Ds[64 * 63];
  const int tid = threadIdx.x;
  {
    const float4* W4 = (const float4*)W;
    float4* Ws4 = (float4*)Ws;
#pragma unroll
    for (int p = 0; p < 4; ++p) Ws4[p * 256 + tid] = W4[p * 256 + tid];
  }
  const float tv = tptr[0];
  const int rbase = blockIdx.x * 64;
  const int limit = min(64, n - rbase) * 63;
  {
    const float4* s4 = (const float4*)(data + (size_t)rbase * 63);
    float4* d4 = (float4*)Ds;
    const int n4 = limit >> 2;
#pragma unroll
    for (int p = 0; p < 4; ++p) {
      int idx = p * 256 + tid;
      if (idx < n4) d4[idx] = s4[idx];
    }
    int tail = limit & 3;
    if (tid < tail) Ds[(n4 << 2) + tid] = data[(size_t)rbase * 63 + (n4 << 2) + tid];
  }
  __syncthreads();
  const int tx = tid & 15, ty = tid >> 4;
  const float* a0p = &Ds[(4 * ty + 0) * 63];
  const float* a1p = &Ds[(4 * ty + 1) * 63];
  const float* a2p = &Ds[(4 * ty + 2) * 63];
  const float* a3p = &Ds[(4 * ty + 3) * 63];
  float acc[4][4];
  {
    float4 w0 = *(const float4*)&Ws[4 * tx];
#pragma unroll
    for (int i = 0; i < 4; ++i) {
      acc[i][0] = tv * w0.x; acc[i][1] = tv * w0.y;
      acc[i][2] = tv * w0.z; acc[i][3] = tv * w0.w;
    }
  }
#pragma unroll 3
  for (int k = 0; k < 63; ++k) {
    float4 w4 = *(const float4*)&Ws[(k + 1) * 64 + 4 * tx];
    float a0 = a0p[k], a1 = a1p[k], a2 = a2p[k], a3 = a3p[k];
    acc[0][0] = fmaf(a0, w4.x, acc[0][0]); acc[0][1] = fmaf(a0, w4.y, acc[0][1]);
    acc[0][2] = fmaf(a0, w4.z, acc[0][2]); acc[0][3] = fmaf(a0, w4.w, acc[0][3]);
    acc[1][0] = fmaf(a1, w4.x, acc[1][0]); acc[1][1] = fmaf(a1, w4.y, acc[1][1]);
    acc[1][2] = fmaf(a1, w4.z, acc[1][2]); acc[1][3] = fmaf(a1, w4.w, acc[1][3]);
    acc[2][0] = fmaf(a2, w4.x, acc[2][0]); acc[2][1] = fmaf(a2, w4.y, acc[2][1]);
    acc[2][2] = fmaf(a2, w4.z, acc[2][2]); acc[2][3] = fmaf(a2, w4.w, acc[2][3]);
    acc[3][0] = fmaf(a3, w4.x, acc[3][0]); acc[3][1] = fmaf(a3, w4.y, acc[3][1]);
    acc[3][2] = fmaf(a3, w4.z, acc[3][2]); acc[3][3] = fmaf(a3, w4.w, acc[3][3]);
  }
#pragma unroll
  for (int i = 0; i < 4; ++i) {
    int r = rbase + 4 * ty + i;
    if (r < n) {
      float di = dis[r];
      __half2* yp = y + (long long)r * 32 + 2 * tx;
      yp[0] = __floats2half2_rn(acc[i][0] * di, acc[i][1] * di);
      yp[1] = __floats2half2_rn(acc[i][2] * di, acc[i][3] * di);
    }
  }
}

// F=64 gather: 8 lanes/edge x 8 features, 8B records, v_fma_mix payload math.
__global__ void gather64h(const __half2* __restrict__ x, const uint2* __restrict__ ce,
                          const int2* __restrict__ node2, const float* __restrict__ dis,
                          const float* __restrict__ b, __half2* __restrict__ o, int n) {
  int i = blockIdx.x * 4 + (threadIdx.x >> 6);
  if (i >= n) return;
  int lane = threadIdx.x & 63;
  int g = lane >> 3;
  int f8 = lane & 7;
  int2 sc = node2[i];
  const uint2* cb = ce + sc.x;
  int c = sc.y;
  const float4* xf = (const float4*)x;
  float4 accA = {0.f, 0.f, 0.f, 0.f}, accB = {0.f, 0.f, 0.f, 0.f};
  int k = g;
  uint2 rec = (k < c) ? cb[k] : make_uint2(0u, 0u);
  while (k < c) {
    int kn = k + 8;
    uint2 recn = (kn < c) ? cb[kn] : make_uint2(0u, 0u);
    float w = __uint_as_float(rec.y);
    F4H8 u; u.f4 = xf[(size_t)rec.x * 8 + f8];
    accA.x = fmaf((float)u.h[0], w, accA.x);
    accA.y = fmaf((float)u.h[1], w, accA.y);
    accA.z = fmaf((float)u.h[2], w, accA.z);
    accA.w = fmaf((float)u.h[3], w, accA.w);
    accB.x = fmaf((float)u.h[4], w, accB.x);
    accB.y = fmaf((float)u.h[5], w, accB.y);
    accB.z = fmaf((float)u.h[6], w, accB.z);
    accB.w = fmaf((float)u.h[7], w, accB.w);
    rec = recn; k = kn;
  }
#pragma unroll
  for (int d = 8; d <= 32; d <<= 1) {
    accA.x += __shfl_xor(accA.x, d, 64); accA.y += __shfl_xor(accA.y, d, 64);
    accA.z += __shfl_xor(accA.z, d, 64); accA.w += __shfl_xor(accA.w, d, 64);
    accB.x += __shfl_xor(accB.x, d, 64); accB.y += __shfl_xor(accB.y, d, 64);
    accB.z += __shfl_xor(accB.z, d, 64); accB.w += __shfl_xor(accB.w, d, 64);
  }
  if (g == 0) {
    F4H8 s; s.f4 = xf[(size_t)i * 8 + f8];
    float di = dis[i];
    float4 b0 = ((const float4*)b)[2 * f8];
    float4 b1 = ((const float4*)b)[2 * f8 + 1];
    float v0 = tanh_fast(di * (accA.x + (float)s.h[0]) + b0.x);
    float v1 = tanh_fast(di * (accA.y + (float)s.h[1]) + b0.y);
    float v2 = tanh_fast(di * (accA.z + (float)s.h[2]) + b0.z);
    float v3 = tanh_fast(di * (accA.w + (float)s.h[3]) + b0.w);
    float v4 = tanh_fast(di * (accB.x + (float)s.h[4]) + b1.x);
    float v5 = tanh_fast(di * (accB.y + (float)s.h[5]) + b1.y);
    float v6 = tanh_fast(di * (accB.z + (float)s.h[6]) + b1.z);
    float v7 = tanh_fast(di * (accB.w + (float)s.h[7]) + b1.w);
    __half2 r0 = __floats2half2_rn(v0, v1);
    __half2 r1 = __floats2half2_rn(v2, v3);
    __half2 r2 = __floats2half2_rn(v4, v5);
    __half2 r3 = __floats2half2_rn(v6, v7);
    float4 st;
    st.x = *reinterpret_cast<float*>(&r0);
    st.y = *reinterpret_cast<float*>(&r1);
    st.z = *reinterpret_cast<float*>(&r2);
    st.w = *reinterpret_cast<float*>(&r3);
    ((float4*)o)[(size_t)i * 8 + f8] = st;
  }
}

// F=32 gather: 4 lanes/edge x 8 features, 8B records, v_fma_mix payload math.
template <bool TANH, bool BIAS, bool POSTDIS, bool FOUT>
__global__ void gather32h(const __half2* __restrict__ x, const uint2* __restrict__ ce,
                          const int2* __restrict__ node2, const float* __restrict__ dis,
                          const float* __restrict__ b, void* __restrict__ outv, int n) {
  int i = blockIdx.x * 4 + (threadIdx.x >> 6);
  if (i >= n) return;
  int lane = threadIdx.x & 63;
  int g = lane >> 2;
  int f8 = lane & 3;
  int2 sc = node2[i];
  const uint2* cb = ce + sc.x;
  int c = sc.y;
  const float4* xf = (const float4*)x;
  float4 accA = {0.f, 0.f, 0.f, 0.f}, accB = {0.f, 0.f, 0.f, 0.f};
  int k = g;
  uint2 rec = (k < c) ? cb[k] : make_uint2(0u, 0u);
  while (k < c) {
    int kn = k + 16;
    uint2 recn = (kn < c) ? cb[kn] : make_uint2(0u, 0u);
    float w = __uint_as_float(rec.y);
    F4H8 u; u.f4 = xf[(size_t)rec.x * 4 + f8];
    accA.x = fmaf((float)u.h[0], w, accA.x);
    accA.y = fmaf((float)u.h[1], w, accA.y);
    accA.z = fmaf((float)u.h[2], w, accA.z);
    accA.w = fmaf((float)u.h[3], w, accA.w);
    accB.x = fmaf((float)u.h[4], w, accB.x);
    accB.y = fmaf((float)u.h[5], w, accB.y);
    accB.z = fmaf((float)u.h[6], w, accB.z);
    accB.w = fmaf((float)u.h[7], w, accB.w);
    rec = recn; k = kn;
  }
#pragma unroll
  for (int d = 4; d <= 32; d <<= 1) {
    accA.x += __shfl_xor(accA.x, d, 64); accA.y += __shfl_xor(accA.y, d, 64);
    accA.z += __shfl_xor(accA.z, d, 64); accA.w += __shfl_xor(accA.w, d, 64);
    accB.x += __shfl_xor(accB.x, d, 64); accB.y += __shfl_xor(accB.y, d, 64);
    accB.z += __shfl_xor(accB.z, d, 64); accB.w += __shfl_xor(accB.w, d, 64);
  }
  if (g == 0) {
    F4H8 s; s.f4 = xf[(size_t)i * 4 + f8];
    float di = dis[i];
    float v0 = di * (accA.x + (float)s.h[0]);
    float v1 = di * (accA.y + (float)s.h[1]);
    float v2 = di * (accA.z + (float)s.h[2]);
    float v3 = di * (accA.w + (float)s.h[3]);
    float v4 = di * (accB.x + (float)s.h[4]);
    float v5 = di * (accB.y + (float)s.h[5]);
    float v6 = di * (accB.z + (float)s.h[6]);
    float v7 = di * (accB.w + (float)s.h[7]);
    if (BIAS) {
      float4 b0 = ((const float4*)b)[2 * f8];
      float4 b1 = ((const float4*)b)[2 * f8 + 1];
      v0 += b0.x; v1 += b0.y; v2 += b0.z; v3 += b0.w;
      v4 += b1.x; v5 += b1.y; v6 += b1.z; v7 += b1.w;
    }
    if (TANH) {
      v0 = tanh_fast(v0); v1 = tanh_fast(v1); v2 = tanh_fast(v2); v3 = tanh_fast(v3);
      v4 = tanh_fast(v4); v5 = tanh_fast(v5); v6 = tanh_fast(v6); v7 = tanh_fast(v7);
    }
    if (POSTDIS) {
      v0 *= di; v1 *= di; v2 *= di; v3 *= di;
      v4 *= di; v5 *= di; v6 *= di; v7 *= di;
    }
    if (FOUT) {
      ((float4*)outv)[(size_t)i * 8 + 2 * f8]     = make_float4(v0, v1, v2, v3);
      ((float4*)outv)[(size_t)i * 8 + 2 * f8 + 1] = make_float4(v4, v5, v6, v7);
    } else {
      __half2 r0 = __floats2half2_rn(v0, v1);
      __half2 r1 = __floats2half2_rn(v2, v3);
      __half2 r2 = __floats2half2_rn(v4, v5);
      __half2 r3 = __floats2half2_rn(v6, v7);
      float4 st;
      st.x = *reinterpret_cast<float*>(&r0);
      st.y = *reinterpret_cast<float*>(&r1);
      st.z = *reinterpret_cast<float*>(&r2);
      st.w = *reinterpret_cast<float*>(&r3);
      ((float4*)outv)[(size_t)i * 4 + f8] = st;
    }
  }
}

// Layer-2 GEMM (register-tiled): z2[n,32]h = dis .* (h1[n,64]h @ W2[64,32]f).
__global__ __launch_bounds__(256) void gemm2t(const __half2* __restrict__ h1,
                                              const float* __restrict__ W,
                                              const float* __restrict__ dis,
                                              __half2* __restrict__ y2, int n) {
  __shared__ float As[64 * 65];
  __shared__ float Ws[64 * 32];
  const int tid = threadIdx.x;
  const int rbase = blockIdx.x * 64;
  const int rows = min(64, n - rbase);
  {
    const float4* W4 = (const float4*)W;
    float4* Ws4 = (float4*)Ws;
    Ws4[tid] = W4[tid];
    Ws4[256 + tid] = W4[256 + tid];
  }
  {
    const __half2* src = h1 + (size_t)rbase * 32;
    const int limit = rows * 32;
#pragma unroll
    for (int p = 0; p < 8; ++p) {
      int idx = p * 256 + tid;
      if (idx < limit) {
        float2 f = __half22float2(src[idx]);
        int r = idx >> 5, k2 = idx & 31;
        As[r * 65 + 2 * k2] = f.x;
        As[r * 65 + 2 * k2 + 1] = f.y;
      }
    }
  }
  __syncthreads();
  const int tx = tid & 7, ty = tid >> 3;
  const float* a0p = &As[(2 * ty) * 65];
  const float* a1p = &As[(2 * ty + 1) * 65];
  float acc0[4] = {0.f, 0.f, 0.f, 0.f};
  float acc1[4] = {0.f, 0.f, 0.f, 0.f};
#pragma unroll 4
  for (int k = 0; k < 64; ++k) {
    float4 w4 = *(const float4*)&Ws[k * 32 + 4 * tx];
    float a0 = a0p[k], a1 = a1p[k];
    acc0[0] = fmaf(a0, w4.x, acc0[0]); acc0[1] = fmaf(a0, w4.y, acc0[1]);
    acc0[2] = fmaf(a0, w4.z, acc0[2]); acc0[3] = fmaf(a0, w4.w, acc0[3]);
    acc1[0] = fmaf(a1, w4.x, acc1[0]); acc1[1] = fmaf(a1, w4.y, acc1[1]);
    acc1[2] = fmaf(a1, w4.z, acc1[2]); acc1[3] = fmaf(a1, w4.w, acc1[3]);
  }
  int r0 = rbase + 2 * ty, r1 = r0 + 1;
  if (r0 < n) {
    float di = dis[r0];
    __half2 h0 = __floats2half2_rn(acc0[0] * di, acc0[1] * di);
    __half2 h1v = __floats2half2_rn(acc0[2] * di, acc0[3] * di);
    float2 st;
    st.x = *reinterpret_cast<float*>(&h0);
    st.y = *reinterpret_cast<float*>(&h1v);
    ((float2*)y2)[(size_t)r0 * 8 + tx] = st;
  }
  if (r1 < n) {
    float di = dis[r1];
    __half2 h0 = __floats2half2_rn(acc1[0] * di, acc1[1] * di);
    __half2 h1v = __floats2half2_rn(acc1[2] * di, acc1[3] * di);
    float2 st;
    st.x = *reinterpret_cast<float*>(&h0);
    st.y = *reinterpret_cast<float*>(&h1v);
    ((float2*)y2)[(size_t)r1 * 8 + tx] = st;
  }
}

// Layer-3 GEMM (register-tiled): out[n,63] = agg[n,32] @ W3[32,63] + b3.
__global__ __launch_bounds__(256) void gemm3_tiled(const float* __restrict__ agg,
                                                   const float* __restrict__ W,
                                                   const float* __restrict__ b,
                                                   float* __restrict__ out, int n) {
  __shared__ float As[64 * 33];
  __shared__ float Ws[32 * 64];
  const int tid = threadIdx.x;
  const int rbase = blockIdx.x * 64;
  const int rows = min(64, n - rbase);
  {
    int r = tid >> 6, j = tid & 63;
#pragma unroll
    for (int p = 0; p < 8; ++p) {
      int rr = r + p * 4;
      if (j < 63) Ws[rr * 64 + j] = W[rr * 63 + j];
    }
    const float* src = agg + (size_t)rbase * 32;
    const int limit = rows * 32;
#pragma unroll
    for (int p = 0; p < 8; ++p) {
      int idx = p * 256 + tid;
      if (idx < limit) As[(idx >> 5) * 33 + (idx & 31)] = src[idx];
    }
  }
  __syncthreads();
  const int tx = tid & 15, ty = tid >> 4;
  const float* a0p = &As[(4 * ty + 0) * 33];
  const float* a1p = &As[(4 * ty + 1) * 33];
  const float* a2p = &As[(4 * ty + 2) * 33];
  const float* a3p = &As[(4 * ty + 3) * 33];
  float bb[4];
#pragma unroll
  for (int jj = 0; jj < 4; ++jj) {
    int j = 4 * tx + jj;
    bb[jj] = (j < 63) ? b[j] : 0.f;
  }
  float acc[4][4];
#pragma unroll
  for (int i = 0; i < 4; ++i) {
    acc[i][0] = bb[0]; acc[i][1] = bb[1]; acc[i][2] = bb[2]; acc[i][3] = bb[3];
  }
#pragma unroll
  for (int k = 0; k < 32; ++k) {
    float4 w4 = *(const float4*)&Ws[k * 64 + 4 * tx];
    float a0 = a0p[k], a1 = a1p[k], a2 = a2p[k], a3 = a3p[k];
    acc[0][0] = fmaf(a0, w4.x, acc[0][0]); acc[0][1] = fmaf(a0, w4.y, acc[0][1]);
    acc[0][2] = fmaf(a0, w4.z, acc[0][2]); acc[0][3] = fmaf(a0, w4.w, acc[0][3]);
    acc[1][0] = fmaf(a1, w4.x, acc[1][0]); acc[1][1] = fmaf(a1, w4.y, acc[1][1]);
    acc[1][2] = fmaf(a1, w4.z, acc[1][2]); acc[1][3] = fmaf(a1, w4.w, acc[1][3]);
    acc[2][0] = fmaf(a2, w4.x, acc[2][0]); acc[2][1] = fmaf(a2, w4.y, acc[2][1]);
    acc[2][2] = fmaf(a2, w4.z, acc[2][2]); acc[2][3] = fmaf(a2, w4.w, acc[2][3]);
    acc[3][0] = fmaf(a3, w4.x, acc[3][0]); acc[3][1] = fmaf(a3, w4.y, acc[3][1]);
    acc[3][2] = fmaf(a3, w4.z, acc[3][2]); acc[3][3] = fmaf(a3, w4.w, acc[3][3]);
  }
#pragma unroll
  for (int i = 0; i < 4; ++i) {
    int r = rbase + 4 * ty + i;
    if (r < n) {
      float* op = out + (size_t)r * 63 + 4 * tx;
#pragma unroll
      for (int jj = 0; jj < 4; ++jj)
        if (4 * tx + jj < 63) op[jj] = acc[i][jj];
    }
  }
}

extern "C" void kernel_launch(void* const* d_in, const int* in_sizes, int n_in,
                              void* d_out, int out_size, void* d_ws, size_t ws_size,
                              hipStream_t stream) {
  const float* t    = (const float*)d_in[0];
  const float* data = (const float*)d_in[1];
  const int*   edges = (const int*)d_in[2];
  const float* ew = (const float*)d_in[4];
  const float* W1 = (const float*)d_in[5];
  const float* b1 = (const float*)d_in[6];
  const float* W2 = (const float*)d_in[7];
  const float* b2 = (const float*)d_in[8];
  const float* W3 = (const float*)d_in[9];
  const float* b3 = (const float*)d_in[10];
  float* out = (float*)d_out;

  const int n  = in_sizes[1] / 63;   // 100000
  const int nE = in_sizes[4];        // 1600000
  const int* row = edges;            // source
  const int* col = edges + nE;       // target
  const int nb = (n + 255) >> 8;     // 391 buckets

  // ws (4B words): dis[n] | node2[2n] | gcur[512] | ce[2*nb*BCAP] | U
  // U = regA[32n] ++ regB[32n]; btmp (uint2, nb*BCAP) aliases U.
  float* ws    = (float*)d_ws;
  float* dis   = ws;
  int2*  node2 = (int2*)(ws + n);
  int*   gcur  = (int*)(ws + 3 * (size_t)n);
  uint2* ce    = (uint2*)(ws + 3 * (size_t)n + 512);
  size_t ceW   = (size_t)nb * BCAP;         // uint2 elements
  float* regA  = (float*)(ce + ceW);
  float* regB  = regA + (size_t)n * 32;
  uint2* btmp  = (uint2*)regA;

  const int B = 256;

  // --- CSR build (bucket sort by target col) ---
  zero_kernel<<<1, 128, 0, stream>>>((int4*)gcur, 128);
  bucket1_kernel<<<cdiv64(nE, CHUNK), 256, 0, stream>>>(row, col, ew, gcur, btmp, nE, nb);
  bucket2_kernel<<<nb, 256, 0, stream>>>(gcur, btmp, ce, node2, dis, n);

  // --- layer 1: z1 = dis.*([t|data]@W1) ; h1 = tanh(dis*(agg+z1)+b1) ---
  gemm1_tiled<<<cdiv64(n, 64), 256, 0, stream>>>(data, t, W1, dis, (__half2*)regA, n);
  gather64h<<<cdiv64(n, 4), B, 0, stream>>>((const __half2*)regA, ce, node2, dis, b1,
                                            (__half2*)regB, n);
  // --- layer 2: z2 = dis.*(h1@W2) ; h2' = dis*tanh(dis*(agg+z2)+b2) ---
  gemm2t<<<cdiv64(n, 64), 256, 0, stream>>>((const __half2*)regB, W2, dis, (__half2*)regA, n);
  gather32h<true, true, true, false><<<cdiv64(n, 4), B, 0, stream>>>(
      (const __half2*)regA, ce, node2, dis, b2, regB, n);
  // --- layer 3: agg = dis*(sum ew h2' + h2') ; out = agg@W3 + b3 ---
  gather32h<false, false, false, true><<<cdiv64(n, 4), B, 0, stream>>>(
      (const __half2*)regB, ce, node2, dis, nullptr, regA, n);
  gemm3_tiled<<<cdiv64(n, 64), 256, 0, stream>>>(regA, W3, b3, out, n);
}